// Round 8
// baseline (1262.039 us; speedup 1.0000x reference)
//
#include <hip/hip_runtime.h>

// NeuralODE: B=1024, D=64, F=8, H=256, 196 substeps x 6 dopri5 stages.
// R17: role-split 8-wave blocks + register UNION. 512 blocks x 512 thr
// (8 waves), 2 rows/block, 2 blocks/CU -> 4 waves/SIMD (2 G1 + 2 G2 from
// 2 independent blocks).
// R16 post-mortem: compressed planes verified (conflicts 9.6e7 -> 0);
// stage=2063cyc, VALU 845 + MFMA 660 overlap across only 2 streams/SIMD
// -- GRID-capped (512 blocks = exactly 2/CU), not register-capped.
// R17 structure:
//  - Waves 0-3 (G2/state): GEMM2 N-tile wv full K=256, dopri5 state,
//    combine, z x-part writes, u rank-8 dot -> yus[256][2] LDS, outputs.
//  - Waves 4-7 (G1): GEMM1 tiles g*4+t x-part K=64 (8 MFMAs), tanh
//    (+yus added at input), h writes.
//  - UNION: both roles need exactly 8 half8 frags -> shared Wf[8]
//    (G1: b1h[t][c]=Wf[t*2+c]; G2: b2h[cc]=Wf[cc]) -> union ~110 regs
//    total (arch+AGPR unified) < 128 -> 4 waves/SIMD fits.
//  - Hazards: z/h/yus single-buffered; producers write only after
//    consumers' reads are barrier-ordered (z read right after B1, written
//    after next B2; h written before B2, read after; yus written before
//    B1, read between B1..B2). 2 barriers/stage + B0/substep (unchanged).
// Go/no-go: OccupancyPercent ~45% = fit; ~23% = reg cliff (known ~1600).
// Numerics: W1/W2 hi fp16 (W1 prescaled 2*log2e), u fp32, fp32 state,
// tanh = 1 - 2*rcp(exp2(y)+1); absmax floor 0.0156 (thresh 0.105).
// MFMA layouts (HW-verified R7/R8): A[m=l&15][k=(l>>4)*8+j],
//   B[k=(l>>4)*8+j][n=l&15], D[row=(l>>4)*4+reg][col=l&15].
// Compressed A-planes: [row0 16B][row1 16B][zero 16B], 48B stride;
// lanes lm>=2 read the zero block (same-address broadcast, conflict-free).

typedef _Float16 half8 __attribute__((ext_vector_type(8)));
typedef float f32x4 __attribute__((ext_vector_type(4)));

#define MFMA16(a, b, c) __builtin_amdgcn_mfma_f32_16x16x32_f16((a), (b), (c), 0, 0, 0)

__global__ __launch_bounds__(512, 1)
void node_kernel(const float* __restrict__ x0,
                 const float* __restrict__ t_eval,
                 const float* __restrict__ t_u,
                 const float* __restrict__ u_batch,
                 const float* __restrict__ W1,
                 const float* __restrict__ b1,
                 const float* __restrict__ W2,
                 const float* __restrict__ b2,
                 float* __restrict__ out)
{
    __shared__ __align__(16) _Float16 zAh[8 * 24];     // z x-part K=64, compressed
    __shared__ __align__(16) _Float16 hAh[32 * 24];    // h K=256, compressed
    __shared__ __align__(16) float    yus[256][2];     // u@W1u per col, rows 0,1
    __shared__ __align__(16) float    ush[6][2][8];    // interp u /stage/row

    const int tid = threadIdx.x;
    const int wv  = tid >> 6;        // wave 0..7
    const int l   = tid & 63;
    const int lm  = l & 15;
    const int lq  = l >> 4;
    const int blk = blockIdx.x;

    const float C2L = 2.8853900817779268f;   // 2*log2(e)

    // --- zero zAh/hAh once: zero blocks stay 0 forever ---
    for (int i = tid; i < (8 * 24) / 2; i += 512)  ((uint32_t*)zAh)[i] = 0u;
    for (int i = tid; i < (32 * 24) / 2; i += 512) ((uint32_t*)hAh)[i] = 0u;

    // --- A-read base: lane lm>=2 -> plane's zero block (broadcast) ---
    const int rowoff = (lm < 2 ? lm : 2) * 16;               // bytes
    const char* zb = (const char*)zAh + lq * 48 + rowoff;
    const char* hb = (const char*)hAh + lq * 48 + rowoff;

    // --- UNION fragment file: G1 b1h[t][c]=Wf[t*2+c], G2 b2h[cc]=Wf[cc] ---
    half8 Wf[8];
    float b1b[4] = {0.f, 0.f, 0.f, 0.f};
    float w1u[8];
    float b2b = 0.0f;
    float xr[2];
    float kfr[5][2];
    const int n2 = (wv & 3) * 16 + lm;       // G2 column; also G1-harmless

    if (wv >= 4) {
        // G1: GEMM1 B-frags, tiles (wv-4)*4+t, x-part K=64, prescaled 2log2e
        const int g = wv - 4;
#pragma unroll
        for (int t = 0; t < 4; ++t) {
            const int n1 = (g * 4 + t) * 16 + lm;
            b1b[t] = b1[n1] * C2L;
#pragma unroll
            for (int c = 0; c < 2; ++c)
#pragma unroll
                for (int j = 0; j < 8; ++j) {
                    const int k = c * 32 + lq * 8 + j;
                    Wf[t * 2 + c][j] = (_Float16)(W1[k * 256 + n1] * C2L);
                }
        }
    } else {
        // G2: GEMM2 B-frags (full K=256), u-weights, state
#pragma unroll
        for (int cc = 0; cc < 8; ++cc)
#pragma unroll
            for (int j = 0; j < 8; ++j) {
                const int k = cc * 32 + lq * 8 + j;
                Wf[cc][j] = (_Float16)W2[k * 64 + n2];
            }
        b2b = b2[n2];
        const int n1u = wv * 64 + l;         // wv<4: col 0..255
#pragma unroll
        for (int f = 0; f < 8; ++f)
            w1u[f] = W1[(64 + f) * 256 + n1u] * C2L;
#pragma unroll
        for (int r = 0; r < 2; ++r) {
            xr[r] = x0[(blk * 2 + r) * 64 + n2];
            if (lq == 0) out[(blk * 2 + r) * 3200 + n2] = xr[r];   // t_eval[0]
        }
    }
    __syncthreads();   // zero-init visible

    float dt_prev = 0.0f;

#pragma unroll 1
    for (int step = 0; step < 196; ++step) {
        const int n = step >> 2;
        const int m = step & 3;
        const float te0 = t_eval[n];
        const float dtc = t_eval[n + 1] - te0;
        const float t   = te0 + dtc * (0.25f * (float)m);
        const float dt  = dtc * 0.25f;

        // --- u prefetch+interp: 96 slots (waves 0,1 = G2) ---
        if (tid < 96) {
            const int s   = tid >> 4;
            const int rem = tid & 15;
            const int mr  = rem >> 3, f = rem & 7;
            float cs;
            switch (s) {
                case 0: cs = 0.0f; break;
                case 1: cs = 1.0f / 5.0f; break;
                case 2: cs = 3.0f / 10.0f; break;
                case 3: cs = 4.0f / 5.0f; break;
                case 4: cs = 8.0f / 9.0f; break;
                default: cs = 1.0f; break;
            }
            const float tsv = t + dt * cs;
            int iu = (int)(tsv * 127.0f);       // == searchsorted-1
            iu = iu < 0 ? 0 : (iu > 126 ? 126 : iu);
            const float ta = t_u[iu];
            const float tb = t_u[iu + 1];
            const float wt = (tsv - ta) / (tb - ta);
            const float* ub = &u_batch[(blk * 2 + mr) * 1024 + iu * 8 + f];
            const float u0v = ub[0];
            const float u1v = ub[8];
            ush[s][mr][f] = fmaf(wt, u1v - u0v, u0v);
        }
        __syncthreads();   // B0: ush ready (h(s5) also ready from prev B2)

#pragma unroll
        for (int s = 0; s < 6; ++s) {
            // ============ G2 segment: GEMM2(prev) + state + z + yu ============
            if (wv < 4) {
                float kv[2] = {0.f, 0.f};
                if (step > 0 || s > 0) {
                    f32x4 aP = {0.f, 0.f, 0.f, 0.f};
                    f32x4 aR = {0.f, 0.f, 0.f, 0.f};
#pragma unroll
                    for (int cc = 0; cc < 8; cc += 2) {
                        const half8 ah0 = *(const half8*)(hb + cc * 192);
                        const half8 ah1 = *(const half8*)(hb + cc * 192 + 192);
                        aP = MFMA16(ah0, Wf[cc], aP);
                        aR = MFMA16(ah1, Wf[cc + 1], aR);
                    }
                    kv[0] = (aP[0] + aR[0]) + b2b;
                    kv[1] = (aP[1] + aR[1]) + b2b;
                }
                float zv[2];
#pragma unroll
                for (int r = 0; r < 2; ++r) {
                    if (s == 0) {
                        if (step > 0)
                            xr[r] = fmaf(dt_prev, (35.0f/384.0f)*kfr[0][r] + (500.0f/1113.0f)*kfr[2][r]
                                            + (125.0f/192.0f)*kfr[3][r] + (-2187.0f/6784.0f)*kfr[4][r]
                                            + (11.0f/84.0f)*kv[r], xr[r]);
                        zv[r] = xr[r];
                    } else if (s == 1) {
                        kfr[0][r] = kv[r];
                        zv[r] = fmaf(dt, kv[r] * (1.0f/5.0f), xr[r]);
                    } else if (s == 2) {
                        kfr[1][r] = kv[r];
                        zv[r] = fmaf(dt, fmaf(3.0f/40.0f, kfr[0][r], (9.0f/40.0f)*kv[r]), xr[r]);
                    } else if (s == 3) {
                        kfr[2][r] = kv[r];
                        zv[r] = fmaf(dt, (44.0f/45.0f)*kfr[0][r] + (-56.0f/15.0f)*kfr[1][r]
                                        + (32.0f/9.0f)*kv[r], xr[r]);
                    } else if (s == 4) {
                        kfr[3][r] = kv[r];
                        zv[r] = fmaf(dt, (19372.0f/6561.0f)*kfr[0][r] + (-25360.0f/2187.0f)*kfr[1][r]
                                        + (64448.0f/6561.0f)*kfr[2][r] + (-212.0f/729.0f)*kv[r], xr[r]);
                    } else {
                        kfr[4][r] = kv[r];
                        zv[r] = fmaf(dt, (9017.0f/3168.0f)*kfr[0][r] + (-355.0f/33.0f)*kfr[1][r]
                                        + (46732.0f/5247.0f)*kfr[2][r] + (49.0f/176.0f)*kfr[3][r]
                                        + (-5103.0f/18656.0f)*kv[r], xr[r]);
                    }
                }
                // output for just-completed step (x updated at s==0)
                if (s == 0 && step > 0 && ((step - 1) & 3) == 3 && lq == 0) {
                    const int ti = ((step - 1) >> 2) + 1;
#pragma unroll
                    for (int r = 0; r < 2; ++r)
                        out[(blk * 2 + r) * 3200 + ti * 64 + n2] = xr[r];
                }
                if (lq == 0) {
#pragma unroll
                    for (int r = 0; r < 2; ++r)
                        zAh[(n2 >> 3) * 24 + r * 8 + (n2 & 7)] = (_Float16)zv[r];
                }
                // u rank-8 dot for cols wv*64 + l, rows 0,1 -> yus
                const float4 uA0 = *(const float4*)&ush[s][0][0];
                const float4 uB0 = *(const float4*)&ush[s][0][4];
                const float4 uA1 = *(const float4*)&ush[s][1][0];
                const float4 uB1 = *(const float4*)&ush[s][1][4];
                float yu0 = uA0.x * w1u[0];
                yu0 = fmaf(uA0.y, w1u[1], yu0);
                yu0 = fmaf(uA0.z, w1u[2], yu0);
                yu0 = fmaf(uA0.w, w1u[3], yu0);
                yu0 = fmaf(uB0.x, w1u[4], yu0);
                yu0 = fmaf(uB0.y, w1u[5], yu0);
                yu0 = fmaf(uB0.z, w1u[6], yu0);
                yu0 = fmaf(uB0.w, w1u[7], yu0);
                float yu1 = uA1.x * w1u[0];
                yu1 = fmaf(uA1.y, w1u[1], yu1);
                yu1 = fmaf(uA1.z, w1u[2], yu1);
                yu1 = fmaf(uA1.w, w1u[3], yu1);
                yu1 = fmaf(uB1.x, w1u[4], yu1);
                yu1 = fmaf(uB1.y, w1u[5], yu1);
                yu1 = fmaf(uB1.z, w1u[6], yu1);
                yu1 = fmaf(uB1.w, w1u[7], yu1);
                const int n1u = wv * 64 + l;
                float2 yw; yw.x = yu0; yw.y = yu1;
                *(float2*)&yus[n1u][0] = yw;
            }
            __syncthreads();   // B1: z + yus ready

            // ============ G1 segment: GEMM1 + tanh + h ============
            if (wv >= 4) {
                const int g = wv - 4;
                const half8 az0 = *(const half8*)(zb);
                const half8 az1 = *(const half8*)(zb + 192);
#pragma unroll
                for (int tt = 0; tt < 4; ++tt) {
                    f32x4 aHH = {0.f, 0.f, 0.f, 0.f};
                    aHH = MFMA16(az0, Wf[tt * 2 + 0], aHH);
                    aHH = MFMA16(az1, Wf[tt * 2 + 1], aHH);
                    const int T = g * 4 + tt;
                    const float2 yu2 = *(const float2*)&yus[T * 16 + lm][0];
                    const float y0 = aHH[0] + yu2.x + b1b[tt];   // 2log2e*(zW1+b1)
                    const float y1 = aHH[1] + yu2.y + b1b[tt];
                    const float e0 = __builtin_amdgcn_exp2f(y0);
                    const float e1 = __builtin_amdgcn_exp2f(y1);
                    const float h0 = fmaf(-2.0f, __builtin_amdgcn_rcpf(e0 + 1.0f), 1.0f);
                    const float h1 = fmaf(-2.0f, __builtin_amdgcn_rcpf(e1 + 1.0f), 1.0f);
                    const int pl = T * 2 + (lm >> 3);
                    if (lq == 0) {
                        hAh[pl * 24 + (lm & 7)]     = (_Float16)h0;
                        hAh[pl * 24 + 8 + (lm & 7)] = (_Float16)h1;
                    }
                }
            }
            __syncthreads();   // B2: h ready
        }
        dt_prev = dt;
    }

    // --- drain: final GEMM2 (k6 of step 195) + x update + last output ---
    if (wv < 4) {
        f32x4 aP = {0.f, 0.f, 0.f, 0.f};
        f32x4 aR = {0.f, 0.f, 0.f, 0.f};
#pragma unroll
        for (int cc = 0; cc < 8; cc += 2) {
            const half8 ah0 = *(const half8*)(hb + cc * 192);
            const half8 ah1 = *(const half8*)(hb + cc * 192 + 192);
            aP = MFMA16(ah0, Wf[cc], aP);
            aR = MFMA16(ah1, Wf[cc + 1], aR);
        }
#pragma unroll
        for (int r = 0; r < 2; ++r) {
            const float k6 = (aP[r] + aR[r]) + b2b;
            xr[r] = fmaf(dt_prev, (35.0f/384.0f)*kfr[0][r] + (500.0f/1113.0f)*kfr[2][r]
                            + (125.0f/192.0f)*kfr[3][r] + (-2187.0f/6784.0f)*kfr[4][r]
                            + (11.0f/84.0f)*k6, xr[r]);
            if (lq == 0)
                out[(blk * 2 + r) * 3200 + 49 * 64 + n2] = xr[r];
        }
    }
}

extern "C" void kernel_launch(void* const* d_in, const int* in_sizes, int n_in,
                              void* d_out, int out_size, void* d_ws, size_t ws_size,
                              hipStream_t stream) {
    const float* x0      = (const float*)d_in[0];
    const float* t_eval  = (const float*)d_in[1];
    const float* t_u     = (const float*)d_in[2];
    const float* u_batch = (const float*)d_in[3];
    const float* W1      = (const float*)d_in[4];
    const float* b1      = (const float*)d_in[5];
    const float* W2      = (const float*)d_in[6];
    const float* b2      = (const float*)d_in[7];
    float* out = (float*)d_out;

    node_kernel<<<dim3(512), dim3(512), 0, stream>>>(
        x0, t_eval, t_u, u_batch, W1, b1, W2, b2, out);
}